// Round 2
// baseline (5342.712 us; speedup 1.0000x reference)
//
#include <hip/hip_runtime.h>
#include <hip/hip_bf16.h>

// Problem constants (from reference)
#define Bb  32
#define Tt  12
#define Nn  5000
#define INc 2
#define Hh  128
#define HORc 12
#define Ee  80000
#define NTt (Bb*Nn)   // 160000

typedef float v2f __attribute__((ext_vector_type(2)));

__device__ __forceinline__ float bf2f(const __hip_bfloat16 v){ return __bfloat162float(v); }

// dtype-flexible load: isbf ? bf16[i] : f32[i]
__device__ __forceinline__ float ldf(const void* p, size_t i, int isbf){
  return isbf ? __bfloat162float(((const __hip_bfloat16*)p)[i]) : ((const float*)p)[i];
}
// int32/int64-flexible edge index read (element i of the logical int array)
__device__ __forceinline__ int eidx(const int* e, int i, int is64){
  return is64 ? e[2*i] : e[i];
}

__device__ __forceinline__ float sigm1(float x){
  x = fmaxf(-30.f, fminf(30.f, x));
  return 1.f/(1.f+__expf(-x));
}
__device__ __forceinline__ v2f sigm2(v2f x){
  v2f r; r.x = sigm1(x.x); r.y = sigm1(x.y); return r;
}
__device__ __forceinline__ float tanh1(float x){
  x = fmaxf(-15.f, fminf(15.f, x));
  float e = __expf(-2.f*x);
  return (1.f-e)/(1.f+e);
}
__device__ __forceinline__ v2f tanh2(v2f x){
  v2f r; r.x = tanh1(x.x); r.y = tanh1(x.y); return r;
}

// ---------------- dtype detection ----------------
// flags[0] = float inputs are bf16 (else fp32); flags[1] = edge_index is int64 (else int32)
__global__ __launch_bounds__(256) void k_detect(const void* W2raw, const int* edge32, int* flags){
  __shared__ int cnt_bf, cnt_odd;
  if (threadIdx.x==0){ cnt_bf=0; cnt_odd=0; }
  __syncthreads();
  {
    unsigned w = ((const unsigned*)W2raw)[threadIdx.x];   // first 1KB, in-bounds either dtype
    unsigned hb = (w>>8)&0x7Fu;                           // low half-word's sign-stripped high byte
    if (hb>=0x34u && hb<=0x3Fu) atomicAdd(&cnt_bf,1);     // bf16 exponent cluster for N(0,0.05)
  }
  if (threadIdx.x < 128){
    if (edge32[2*threadIdx.x+1] != 0) atomicAdd(&cnt_odd,1); // int64 high words are all zero
  }
  __syncthreads();
  if (threadIdx.x==0){
    flags[0] = (cnt_bf >= 128) ? 1 : 0;
    flags[1] = (cnt_odd == 0) ? 1 : 0;
  }
}

// ---------------- graph precompute ----------------

__global__ __launch_bounds__(256) void k_deg_cnt(const int* __restrict__ edge, int* deg, int* cnt,
                                                 const int* __restrict__ flags){
  int id = blockIdx.x*256 + threadIdx.x;
  int is64 = flags[1];
  if (id < Ee){
    atomicAdd(&deg[eidx(edge, id, is64)], 1);      // deg counts src occurrences
    atomicAdd(&cnt[eidx(edge, Ee+id, is64)], 1);   // in-degree by dst (for CSR)
  }
}

__global__ __launch_bounds__(256) void k_dis(const int* __restrict__ deg, float* dis){
  int id = blockIdx.x*256 + threadIdx.x;
  if (id < Nn){
    int d = deg[id];
    dis[id] = d > 0 ? rsqrtf((float)d) : 0.f;
  }
}

__global__ __launch_bounds__(1024) void k_scan(const int* __restrict__ cnt, int* rowptr){
  __shared__ int part[1024];
  int t = threadIdx.x;
  int base = t*5;
  int s = 0;
  #pragma unroll
  for (int j=0;j<5;j++){ int idx=base+j; if (idx<Nn) s += cnt[idx]; }
  part[t] = s; __syncthreads();
  for (int off=1; off<1024; off<<=1){
    int add = (t>=off) ? part[t-off] : 0;
    __syncthreads();
    part[t] += add;
    __syncthreads();
  }
  int run = (t>0) ? part[t-1] : 0;
  #pragma unroll
  for (int j=0;j<5;j++){
    int idx = base+j;
    if (idx < Nn){ rowptr[idx] = run; run += cnt[idx]; }
  }
  if (t == 1023) rowptr[Nn] = part[1023];
}

__global__ __launch_bounds__(256) void k_fill(const int* __restrict__ edge,
                                              const int* __restrict__ rowptr,
                                              int* fillc, int* csr,
                                              const int* __restrict__ flags){
  int id = blockIdx.x*256 + threadIdx.x;
  int is64 = flags[1];
  if (id < Ee){
    int d = eidx(edge, Ee+id, is64);
    int pos = atomicAdd(&fillc[d], 1);
    csr[rowptr[d] + pos] = eidx(edge, id, is64);
  }
}

// ---------------- weight precompute ----------------
// Interleaved layout for the gate loops: element pair {f, f+64} stored as float2 at [.. *64 + (f&63)]

__global__ __launch_bounds__(256) void k_wconv(
  const void* __restrict__ W2, const void* __restrict__ Wz,
  const void* __restrict__ Wr, const void* __restrict__ Wc,
  const void* __restrict__ b2,
  float* W2d, float* W21, float* W22, float* Wzb, float* Wrb, float* Wcb, float* b2i,
  const int* __restrict__ flags)
{
  int id = blockIdx.x*256 + threadIdx.x;
  int isbf = flags[0];
  if (id < 8192){
    int k = id >> 6, l = id & 63;
    #pragma unroll
    for (int c=0;c<2;c++){
      int f = l + 64*c;
      W2d[(k*64+l)*2+c] = ldf(W2,(0*128+k)*128+f,isbf) - ldf(W2,(2*128+k)*128+f,isbf);
      W21[k*128+f]      = ldf(W2,(1*128+k)*128+f,isbf);
      W22[k*128+f]      = ldf(W2,(2*128+k)*128+f,isbf);
      Wzb[(k*64+l)*2+c] = ldf(Wz,(128+k)*128+f,isbf);
      Wrb[(k*64+l)*2+c] = ldf(Wr,(128+k)*128+f,isbf);
      Wcb[(k*64+l)*2+c] = ldf(Wc,(128+k)*128+f,isbf);
    }
    if (id < 64){
      b2i[id*2+0] = ldf(b2,id,isbf);
      b2i[id*2+1] = ldf(b2,id+64,isbf);
    }
  }
}

__global__ __launch_bounds__(256) void k_beff(
  const void* __restrict__ b1,
  const void* __restrict__ Wz, const void* __restrict__ bz,
  const void* __restrict__ Wr, const void* __restrict__ br,
  const void* __restrict__ Wc, const void* __restrict__ bc,
  float* beff, const int* __restrict__ flags)
{
  int id = blockIdx.x*256 + threadIdx.x;
  int isbf = flags[0];
  if (id < 384){
    int g = id >> 7, f = id & 127;
    const void* W  = (g==0)?Wz:((g==1)?Wr:Wc);
    const void* bb = (g==0)?bz:((g==1)?br:bc);
    float acc = ldf(bb,f,isbf);
    for (int j=0;j<128;j++) acc += ldf(b1,j,isbf)*ldf(W,j*128+f,isbf);
    beff[g*128 + (f&63)*2 + (f>>6)] = acc;
  }
}

// Mi[g][q=kk*2+c][f] = sum_j W1[kk][c][j] * Wgate[j][f]   (ic-folding, rank-2 trick)
__global__ __launch_bounds__(256) void k_mfold(
  const void* __restrict__ W1,
  const void* __restrict__ Wz, const void* __restrict__ Wr,
  const void* __restrict__ Wc, float* Mi, const int* __restrict__ flags)
{
  int id = blockIdx.x*256 + threadIdx.x;
  int isbf = flags[0];
  if (id < 2304){
    int f = id & 127, r = id >> 7;     // r = g*6 + q
    int g = r / 6, q = r - g*6;        // q = kk*2 + c
    const void* W = (g==0)?Wz:((g==1)?Wr:Wc);
    float acc = 0.f;
    for (int j=0;j<128;j++) acc += ldf(W1,q*128+j,isbf) * ldf(W,j*128+f,isbf);
    Mi[(g*6+q)*128 + (f&63)*2 + (f>>6)] = acc;
  }
}

// ---------------- x propagation (all timesteps at once) ----------------

__global__ __launch_bounds__(256) void k_px1(
  const void* __restrict__ x, const float* __restrict__ dis,
  const int* __restrict__ rowptr, const int* __restrict__ csr, float* __restrict__ px1,
  const int* __restrict__ flags)
{
  int id = blockIdx.x*256 + threadIdx.x;
  int isbf = flags[0];
  if (id < Tt*Nn){
    int t = id / Nn, n = id - t*Nn;
    int e0 = rowptr[n], e1 = rowptr[n+1];
    float a0=0.f, a1=0.f;
    for (int e=e0;e<e1;e++){
      int s = csr[e]; float ds = dis[s];
      size_t xb = (size_t)(t*Nn+s)*2;   // batch 0 slice
      a0 += ds*ldf(x,xb+0,isbf); a1 += ds*ldf(x,xb+1,isbf);
    }
    float dn = -dis[n];
    px1[id*2+0] = dn*a0; px1[id*2+1] = dn*a1;
  }
}

__global__ __launch_bounds__(256) void k_px2(
  const float* __restrict__ px1, const float* __restrict__ dis,
  const int* __restrict__ rowptr, const int* __restrict__ csr, float* __restrict__ px2)
{
  int id = blockIdx.x*256 + threadIdx.x;
  if (id < Tt*Nn){
    int t = id / Nn, n = id - t*Nn;
    int e0 = rowptr[n], e1 = rowptr[n+1];
    float a0=0.f, a1=0.f;
    for (int e=e0;e<e1;e++){
      int s = csr[e]; float ds = dis[s];
      const float* pp = px1 + (size_t)(t*Nn+s)*2;
      a0 += ds*pp[0]; a1 += ds*pp[1];
    }
    float dn = -dis[n];
    px2[id*2+0] = dn*a0; px2[id*2+1] = dn*a1;
  }
}

// ---------------- per-step h propagation (first N nodes only) ----------------

__global__ __launch_bounds__(128) void k_ph1(
  const float* __restrict__ h, const float* __restrict__ dis,
  const int* __restrict__ rowptr, const int* __restrict__ csr, float* __restrict__ ph1)
{
  int n = blockIdx.x, f = threadIdx.x;
  int e0 = rowptr[n], e1 = rowptr[n+1];
  float acc = 0.f;
  for (int e=e0;e<e1;e++){
    int s = csr[e];
    acc += dis[s] * h[(size_t)s*128 + f];
  }
  ph1[n*128 + f] = -dis[n]*acc;
}

// ph2 = prop(ph1); hcx = ph1@W2[1] + 2*ph2@W2[2]  (interleaved output)
__global__ __launch_bounds__(128) void k_ph2hcx(
  const float* __restrict__ ph1, const float* __restrict__ dis,
  const int* __restrict__ rowptr, const int* __restrict__ csr,
  const float* __restrict__ W21, const float* __restrict__ W22,
  float* __restrict__ hcx)
{
  __shared__ float s1[128], s2[128];
  int n = blockIdx.x, f = threadIdx.x;
  int e0 = rowptr[n], e1 = rowptr[n+1];
  float acc = 0.f;
  for (int e=e0;e<e1;e++){
    int s = csr[e];
    acc += dis[s] * ph1[s*128 + f];
  }
  s2[f] = -dis[n]*acc;
  s1[f] = ph1[n*128 + f];
  __syncthreads();
  float a = 0.f;
  for (int k=0;k<128;k++)
    a += s1[k]*W21[k*128+f] + 2.f*s2[k]*W22[k*128+f];
  hcx[n*128 + (f&63)*2 + (f>>6)] = a;
}

// ---------------- fused GRU step ----------------
// block = 256 threads (4 waves), 32 nodes/block; wave w owns nodes w*8..w*8+7,
// lane l owns features {l, l+64} as a float2.

__global__ __launch_bounds__(256) void k_main(
    float* __restrict__ h, const void* __restrict__ x,
    const float* __restrict__ px1, const float* __restrict__ px2,
    const float* __restrict__ hcx,
    const float* __restrict__ W2d, const float* __restrict__ Wzb,
    const float* __restrict__ Wrb, const float* __restrict__ Wcb,
    const float* __restrict__ Mi, const float* __restrict__ beff,
    const float* __restrict__ b2i, const int* __restrict__ flags, int t)
{
  __shared__ float lh[32*128];
  __shared__ float lhc[32*128];
  __shared__ float lu[32*8];
  int tid = threadIdx.x;
  int base = blockIdx.x*32;

  { // stage h tile
    const float4* hg = (const float4*)(h + (size_t)base*128);
    float4* lh4 = (float4*)lh;
    #pragma unroll
    for (int r=0;r<4;r++) lh4[tid + r*256] = hg[tid + r*256];
  }

  if (tid < 32){ // stage per-node u-vectors (Cheb terms of the 2-dim input)
    int isbf = flags[0];
    int i = base + tid;
    int b = i / Nn, n = i - b*Nn;
    size_t xb = ((size_t)(b*Tt + t)*Nn + n)*INc;
    float x0 = ldf(x,xb+0,isbf), x1 = ldf(x,xb+1,isbf);
    float u10=0.f,u11=0.f,u20=-x0,u21=-x1;       // nodes >= N: Tx1=0, Tx2=-x
    if (i < Nn){
      float p10 = px1[(t*Nn+i)*2+0], p11 = px1[(t*Nn+i)*2+1];
      float p20 = px2[(t*Nn+i)*2+0], p21 = px2[(t*Nn+i)*2+1];
      u10 = p10; u11 = p11; u20 = 2.f*p20 - x0; u21 = 2.f*p21 - x1;
    }
    float* up = lu + tid*8;
    up[0]=x0; up[1]=x1; up[2]=u10; up[3]=u11; up[4]=u20; up[5]=u21;
  }
  __syncthreads();

  int w = tid >> 6, l = tid & 63;
  int n0 = w*8;
  const v2f* W2dv = (const v2f*)W2d;
  const v2f* Wzbv = (const v2f*)Wzb;
  const v2f* Wrbv = (const v2f*)Wrb;
  const v2f* Wcbv = (const v2f*)Wcb;
  const v2f* Miv  = (const v2f*)Mi;
  const v2f* beffv= (const v2f*)beff;

  // ---- stage 1: hc = h@(W2[0]-W2[2]) + b2 (+ graph correction for i<N)
  v2f hc[8];
  {
    v2f bb = ((const v2f*)b2i)[l];
    #pragma unroll
    for (int n=0;n<8;n++){
      hc[n] = bb;
      int gi = base + n0 + n;
      if (gi < Nn) hc[n] += ((const v2f*)hcx)[gi*64 + l];
    }
    for (int kk=0; kk<128; kk+=4){
      v2f w0 = W2dv[(kk+0)*64+l], w1 = W2dv[(kk+1)*64+l],
          w2 = W2dv[(kk+2)*64+l], w3 = W2dv[(kk+3)*64+l];
      #pragma unroll
      for (int n=0;n<8;n++){
        float4 hv = *(const float4*)&lh[(n0+n)*128 + kk];  // wave-uniform broadcast
        hc[n] += hv.x*w0 + hv.y*w1 + hv.z*w2 + hv.w*w3;
      }
    }
    #pragma unroll
    for (int n=0;n<8;n++){
      lhc[(n0+n)*128 + l]      = hc[n].x;
      lhc[(n0+n)*128 + l + 64] = hc[n].y;
    }
  }
  __syncthreads();

  // ---- stage 2a: z, r preactivations
  v2f az[8], ar[8];
  {
    v2f bz = beffv[0*64+l], br = beffv[1*64+l];
    #pragma unroll
    for (int n=0;n<8;n++){
      const float* up = lu + (n0+n)*8;
      v2f sz = bz, sr = br;
      #pragma unroll
      for (int q=0;q<6;q++){
        float uv = up[q];
        sz += uv*Miv[(0*6+q)*64+l];
        sr += uv*Miv[(1*6+q)*64+l];
      }
      az[n]=sz; ar[n]=sr;
    }
    for (int kk=0;kk<128;kk+=4){
      v2f z0=Wzbv[(kk+0)*64+l], z1=Wzbv[(kk+1)*64+l], z2=Wzbv[(kk+2)*64+l], z3=Wzbv[(kk+3)*64+l];
      v2f r0=Wrbv[(kk+0)*64+l], r1=Wrbv[(kk+1)*64+l], r2=Wrbv[(kk+2)*64+l], r3=Wrbv[(kk+3)*64+l];
      #pragma unroll
      for (int n=0;n<8;n++){
        float4 c4 = *(const float4*)&lhc[(n0+n)*128 + kk];
        az[n] += c4.x*z0 + c4.y*z1 + c4.z*z2 + c4.w*z3;
        ar[n] += c4.x*r0 + c4.y*r1 + c4.z*r2 + c4.w*r3;
      }
    }
  }

  // ---- z, r; write r*hc over lhc
  v2f zz[8];
  __syncthreads();   // everyone done reading lhc
  #pragma unroll
  for (int n=0;n<8;n++){
    zz[n] = sigm2(az[n]);
    v2f rr = sigm2(ar[n]);
    v2f rhc = rr * hc[n];
    lhc[(n0+n)*128 + l]      = rhc.x;
    lhc[(n0+n)*128 + l + 64] = rhc.y;
  }
  __syncthreads();

  // ---- stage 2b: candidate + blend
  v2f ac[8];
  {
    v2f bc = beffv[2*64+l];
    #pragma unroll
    for (int n=0;n<8;n++){
      const float* up = lu + (n0+n)*8;
      v2f s = bc;
      #pragma unroll
      for (int q=0;q<6;q++) s += up[q]*Miv[(2*6+q)*64+l];
      ac[n]=s;
    }
    for (int kk=0;kk<128;kk+=4){
      v2f c0=Wcbv[(kk+0)*64+l], c1=Wcbv[(kk+1)*64+l], c2=Wcbv[(kk+2)*64+l], c3=Wcbv[(kk+3)*64+l];
      #pragma unroll
      for (int n=0;n<8;n++){
        float4 c4 = *(const float4*)&lhc[(n0+n)*128 + kk];
        ac[n] += c4.x*c0 + c4.y*c1 + c4.z*c2 + c4.w*c3;
      }
    }
  }
  #pragma unroll
  for (int n=0;n<8;n++){
    v2f ht = tanh2(ac[n]);
    v2f hold; hold.x = lh[(n0+n)*128 + l]; hold.y = lh[(n0+n)*128 + l + 64];
    v2f hnew = zz[n]*hold + (1.f - zz[n])*ht;
    float* hp = h + (size_t)(base+n0+n)*128;
    hp[l] = hnew.x; hp[l+64] = hnew.y;
  }
}

// ---------------- output projection ----------------

__global__ __launch_bounds__(256) void k_out(
  const float* __restrict__ h, const void* __restrict__ Wo,
  const void* __restrict__ bo, void* __restrict__ out,
  const int* __restrict__ flags)
{
  int i = blockIdx.x*256 + threadIdx.x;
  int isbf = flags[0];
  if (i < NTt){
    float acc[HORc];
    #pragma unroll
    for (int j=0;j<HORc;j++) acc[j] = ldf(bo,j,isbf);
    const float* hp = h + (size_t)i*128;
    for (int k=0;k<128;k++){
      float hv = hp[k];
      #pragma unroll
      for (int j=0;j<HORc;j++) acc[j] += hv * ldf(Wo,k*HORc+j,isbf);
    }
    int b = i / Nn, n = i - b*Nn;
    #pragma unroll
    for (int j=0;j<HORc;j++){
      size_t oi = (size_t)(b*HORc+j)*Nn + n;
      if (isbf) ((__hip_bfloat16*)out)[oi] = __float2bfloat16(acc[j]);
      else      ((float*)out)[oi] = acc[j];
    }
  }
}

// ---------------- host ----------------

extern "C" void kernel_launch(void* const* d_in, const int* in_sizes, int n_in,
                              void* d_out, int out_size, void* d_ws, size_t ws_size,
                              hipStream_t stream) {
  (void)in_sizes; (void)n_in; (void)out_size; (void)ws_size;
  const void* x   = d_in[0];
  const int*  edge= (const int*)d_in[1];
  const void* W1  = d_in[2];
  const void* b1  = d_in[3];
  const void* W2  = d_in[4];
  const void* b2  = d_in[5];
  const void* Wz  = d_in[6];
  const void* bz  = d_in[7];
  const void* Wr  = d_in[8];
  const void* br  = d_in[9];
  const void* Wc  = d_in[10];
  const void* bc  = d_in[11];
  const void* Wo  = d_in[12];
  const void* bo  = d_in[13];

  char* ws = (char*)d_ws;
  size_t off = 0;
  auto alloc = [&](size_t bytes)->char*{
    char* p = ws + off;
    off += (bytes + 255) & ~(size_t)255;
    return p;
  };
  float* h     = (float*)alloc((size_t)NTt*128*4);   // 81.92 MB, zeroed
  int*   deg   = (int*)  alloc(Nn*4);                // zeroed
  int*   cnt   = (int*)  alloc(Nn*4);                // zeroed
  int*   fillc = (int*)  alloc(Nn*4);                // zeroed
  size_t zlen = off;
  int*   flags = (int*)  alloc(16*4);
  float* dis   = (float*)alloc(Nn*4);
  int*   rowptr= (int*)  alloc((Nn+1)*4);
  int*   csr   = (int*)  alloc(Ee*4);
  float* px1   = (float*)alloc((size_t)Tt*Nn*2*4);
  float* px2   = (float*)alloc((size_t)Tt*Nn*2*4);
  float* ph1   = (float*)alloc((size_t)Nn*128*4);
  float* hcx   = (float*)alloc((size_t)Nn*128*4);
  float* W2d   = (float*)alloc(128*128*4);
  float* W21   = (float*)alloc(128*128*4);
  float* W22   = (float*)alloc(128*128*4);
  float* Wzb   = (float*)alloc(128*128*4);
  float* Wrb   = (float*)alloc(128*128*4);
  float* Wcb   = (float*)alloc(128*128*4);
  float* Mi    = (float*)alloc(18*128*4);
  float* beff  = (float*)alloc(3*128*4);
  float* b2i   = (float*)alloc(128*4);

  hipMemsetAsync(d_ws, 0, zlen, stream);

  k_detect <<<1,256,0,stream>>>(W2, edge, flags);
  k_deg_cnt<<<(Ee+255)/256,256,0,stream>>>(edge, deg, cnt, flags);
  k_dis    <<<(Nn+255)/256,256,0,stream>>>(deg, dis);
  k_scan   <<<1,1024,0,stream>>>(cnt, rowptr);
  k_fill   <<<(Ee+255)/256,256,0,stream>>>(edge, rowptr, fillc, csr, flags);
  k_wconv  <<<32,256,0,stream>>>(W2, Wz, Wr, Wc, b2, W2d, W21, W22, Wzb, Wrb, Wcb, b2i, flags);
  k_beff   <<<2,256,0,stream>>>(b1, Wz, bz, Wr, br, Wc, bc, beff, flags);
  k_mfold  <<<9,256,0,stream>>>(W1, Wz, Wr, Wc, Mi, flags);
  k_px1    <<<(Tt*Nn+255)/256,256,0,stream>>>(x, dis, rowptr, csr, px1, flags);
  k_px2    <<<(Tt*Nn+255)/256,256,0,stream>>>(px1, dis, rowptr, csr, px2);

  for (int t=0; t<Tt; ++t){
    k_ph1   <<<Nn,128,0,stream>>>(h, dis, rowptr, csr, ph1);
    k_ph2hcx<<<Nn,128,0,stream>>>(ph1, dis, rowptr, csr, W21, W22, hcx);
    k_main  <<<NTt/32,256,0,stream>>>(h, x, px1, px2, hcx,
                                      W2d, Wzb, Wrb, Wcb, Mi, beff, b2i, flags, t);
  }

  k_out<<<(NTt+255)/256,256,0,stream>>>(h, Wo, bo, d_out, flags);
}

// Round 3
// 2308.215 us; speedup vs baseline: 2.3147x; 2.3147x over previous
//
#include <hip/hip_runtime.h>
#include <hip/hip_bf16.h>

// Problem constants (from reference)
#define Bb  32
#define Tt  12
#define Nn  5000
#define INc 2
#define Hh  128
#define HORc 12
#define Ee  80000
#define NTt (Bb*Nn)   // 160000

typedef float v2f __attribute__((ext_vector_type(2)));
typedef float f4  __attribute__((ext_vector_type(4)));
typedef _Float16 h8 __attribute__((ext_vector_type(8)));
typedef _Float16 h4 __attribute__((ext_vector_type(4)));

// LDS per-wave layout (halfs): hL[16][172] | hcL[16][172] | zL[16][136]
#define HSTRIDE 172
#define ZSTRIDE 136
#define WAVE_LDS (16*HSTRIDE*2 + 16*ZSTRIDE)   // 7680 halfs = 15360 B

__device__ __forceinline__ float bf2f(const __hip_bfloat16 v){ return __bfloat162float(v); }

// dtype-flexible load: isbf ? bf16[i] : f32[i]
__device__ __forceinline__ float ldf(const void* p, size_t i, int isbf){
  return isbf ? __bfloat162float(((const __hip_bfloat16*)p)[i]) : ((const float*)p)[i];
}
// int32/int64-flexible edge index read (element i of the logical int array)
__device__ __forceinline__ int eidx(const int* e, int i, int is64){
  return is64 ? e[2*i] : e[i];
}

__device__ __forceinline__ float sigm1(float x){
  x = fmaxf(-30.f, fminf(30.f, x));
  return 1.f/(1.f+__expf(-x));
}
__device__ __forceinline__ float tanh1(float x){
  x = fmaxf(-15.f, fminf(15.f, x));
  float e = __expf(-2.f*x);
  return (1.f-e)/(1.f+e);
}

// ---------------- dtype detection ----------------
// flags[0] = float inputs are bf16 (else fp32); flags[1] = edge_index is int64 (else int32)
__global__ __launch_bounds__(256) void k_detect(const void* W2raw, const int* edge32, int* flags){
  __shared__ int cnt_bf, cnt_odd;
  if (threadIdx.x==0){ cnt_bf=0; cnt_odd=0; }
  __syncthreads();
  {
    unsigned w = ((const unsigned*)W2raw)[threadIdx.x];   // first 1KB, in-bounds either dtype
    unsigned hb = (w>>8)&0x7Fu;                           // low half-word's sign-stripped high byte
    if (hb>=0x34u && hb<=0x3Fu) atomicAdd(&cnt_bf,1);     // bf16 exponent cluster for N(0,0.05)
  }
  if (threadIdx.x < 128){
    if (edge32[2*threadIdx.x+1] != 0) atomicAdd(&cnt_odd,1); // int64 high words are all zero
  }
  __syncthreads();
  if (threadIdx.x==0){
    flags[0] = (cnt_bf >= 128) ? 1 : 0;
    flags[1] = (cnt_odd == 0) ? 1 : 0;
  }
}

// ---------------- graph precompute ----------------

__global__ __launch_bounds__(256) void k_deg_cnt(const int* __restrict__ edge, int* deg, int* cnt,
                                                 const int* __restrict__ flags){
  int id = blockIdx.x*256 + threadIdx.x;
  int is64 = flags[1];
  if (id < Ee){
    atomicAdd(&deg[eidx(edge, id, is64)], 1);      // deg counts src occurrences
    atomicAdd(&cnt[eidx(edge, Ee+id, is64)], 1);   // in-degree by dst (for CSR)
  }
}

__global__ __launch_bounds__(256) void k_dis(const int* __restrict__ deg, float* dis){
  int id = blockIdx.x*256 + threadIdx.x;
  if (id < Nn){
    int d = deg[id];
    dis[id] = d > 0 ? rsqrtf((float)d) : 0.f;
  }
}

__global__ __launch_bounds__(1024) void k_scan(const int* __restrict__ cnt, int* rowptr){
  __shared__ int part[1024];
  int t = threadIdx.x;
  int base = t*5;
  int s = 0;
  #pragma unroll
  for (int j=0;j<5;j++){ int idx=base+j; if (idx<Nn) s += cnt[idx]; }
  part[t] = s; __syncthreads();
  for (int off=1; off<1024; off<<=1){
    int add = (t>=off) ? part[t-off] : 0;
    __syncthreads();
    part[t] += add;
    __syncthreads();
  }
  int run = (t>0) ? part[t-1] : 0;
  #pragma unroll
  for (int j=0;j<5;j++){
    int idx = base+j;
    if (idx < Nn){ rowptr[idx] = run; run += cnt[idx]; }
  }
  if (t == 1023) rowptr[Nn] = part[1023];
}

__global__ __launch_bounds__(256) void k_fill(const int* __restrict__ edge,
                                              const int* __restrict__ rowptr,
                                              int* fillc, int* csr,
                                              const int* __restrict__ flags){
  int id = blockIdx.x*256 + threadIdx.x;
  int is64 = flags[1];
  if (id < Ee){
    int d = eidx(edge, Ee+id, is64);
    int pos = atomicAdd(&fillc[d], 1);
    csr[rowptr[d] + pos] = eidx(edge, id, is64);
  }
}

// ---------------- weight precompute ----------------
// Wext: 4 stage matrices, each [128 f][160 k] fp16 row-major (A-operand, transposed weights).
//  stage 0 (hc):  k<128: W2[0][k][f]-W2[2][k][f]; k=128: b2[f]; rest 0
//  stage 1/2/3 (z/r/c): k<128: Wg[128+k][f]; k=128+q: Mi_g[q][f] (rank-2 input fold);
//                       k=134: beff_g[f] = bg[f] + b1@Wg_ic; rest 0
__global__ __launch_bounds__(256) void k_wext(
  const void* __restrict__ W1, const void* __restrict__ b1,
  const void* __restrict__ W2, const void* __restrict__ b2,
  const void* __restrict__ Wz, const void* __restrict__ bz,
  const void* __restrict__ Wr, const void* __restrict__ br,
  const void* __restrict__ Wc, const void* __restrict__ bc,
  _Float16* __restrict__ Wext, const int* __restrict__ flags)
{
  int id = blockIdx.x*256 + threadIdx.x;
  if (id >= 512) return;
  int isbf = flags[0];
  int s = id >> 7, f = id & 127;
  _Float16* row = Wext + (size_t)(s*128 + f)*160;
  for (int k=135;k<160;k++) row[k] = (_Float16)0.f;
  if (s == 0){
    for (int j=0;j<128;j++)
      row[j] = (_Float16)(ldf(W2,(size_t)j*128+f,isbf) - ldf(W2,(size_t)(2*128+j)*128+f,isbf));
    row[128] = (_Float16)ldf(b2,f,isbf);
    for (int k=129;k<135;k++) row[k] = (_Float16)0.f;
  } else {
    const void* Wg = (s==1)?Wz:((s==2)?Wr:Wc);
    const void* bg = (s==1)?bz:((s==2)?br:bc);
    for (int j=0;j<128;j++)
      row[j] = (_Float16)ldf(Wg,(size_t)(128+j)*128+f,isbf);
    for (int q=0;q<6;q++){
      float acc = 0.f;
      for (int j=0;j<128;j++) acc += ldf(W1,q*128+j,isbf)*ldf(Wg,(size_t)j*128+f,isbf);
      row[128+q] = (_Float16)acc;
    }
    float acc = ldf(bg,f,isbf);
    for (int j=0;j<128;j++) acc += ldf(b1,j,isbf)*ldf(Wg,(size_t)j*128+f,isbf);
    row[134] = (_Float16)acc;
  }
}

// fp32 copies of W2[1], W2[2] for the hcx kernel
__global__ __launch_bounds__(256) void k_w2(const void* __restrict__ W2,
                                            float* W21, float* W22,
                                            const int* __restrict__ flags){
  int id = blockIdx.x*256 + threadIdx.x;
  int isbf = flags[0];
  if (id < 16384){
    W21[id] = ldf(W2, (size_t)16384 + id, isbf);
    W22[id] = ldf(W2, (size_t)32768 + id, isbf);
  }
}

// ---------------- x propagation (all timesteps at once) ----------------

__global__ __launch_bounds__(256) void k_px1(
  const void* __restrict__ x, const float* __restrict__ dis,
  const int* __restrict__ rowptr, const int* __restrict__ csr, float* __restrict__ px1,
  const int* __restrict__ flags)
{
  int id = blockIdx.x*256 + threadIdx.x;
  int isbf = flags[0];
  if (id < Tt*Nn){
    int t = id / Nn, n = id - t*Nn;
    int e0 = rowptr[n], e1 = rowptr[n+1];
    float a0=0.f, a1=0.f;
    for (int e=e0;e<e1;e++){
      int s = csr[e]; float ds = dis[s];
      size_t xb = (size_t)(t*Nn+s)*2;   // batch 0 slice
      a0 += ds*ldf(x,xb+0,isbf); a1 += ds*ldf(x,xb+1,isbf);
    }
    float dn = -dis[n];
    px1[id*2+0] = dn*a0; px1[id*2+1] = dn*a1;
  }
}

__global__ __launch_bounds__(256) void k_px2(
  const float* __restrict__ px1, const float* __restrict__ dis,
  const int* __restrict__ rowptr, const int* __restrict__ csr, float* __restrict__ px2)
{
  int id = blockIdx.x*256 + threadIdx.x;
  if (id < Tt*Nn){
    int t = id / Nn, n = id - t*Nn;
    int e0 = rowptr[n], e1 = rowptr[n+1];
    float a0=0.f, a1=0.f;
    for (int e=e0;e<e1;e++){
      int s = csr[e]; float ds = dis[s];
      const float* pp = px1 + (size_t)(t*Nn+s)*2;
      a0 += ds*pp[0]; a1 += ds*pp[1];
    }
    float dn = -dis[n];
    px2[id*2+0] = dn*a0; px2[id*2+1] = dn*a1;
  }
}

// ---------------- per-step h propagation (first N nodes only) ----------------

__global__ __launch_bounds__(128) void k_ph1(
  const float* __restrict__ h, const float* __restrict__ dis,
  const int* __restrict__ rowptr, const int* __restrict__ csr, float* __restrict__ ph1)
{
  int n = blockIdx.x, f = threadIdx.x;
  int e0 = rowptr[n], e1 = rowptr[n+1];
  float acc = 0.f;
  for (int e=e0;e<e1;e++){
    int s = csr[e];
    acc += dis[s] * h[(size_t)s*128 + f];
  }
  ph1[n*128 + f] = -dis[n]*acc;
}

// ph2 = prop(ph1); hcx = ph1@W2[1] + 2*ph2@W2[2]   (plain [n][f] fp32 output)
__global__ __launch_bounds__(128) void k_ph2hcx(
  const float* __restrict__ ph1, const float* __restrict__ dis,
  const int* __restrict__ rowptr, const int* __restrict__ csr,
  const float* __restrict__ W21, const float* __restrict__ W22,
  float* __restrict__ hcx)
{
  __shared__ float s1[128], s2[128];
  int n = blockIdx.x, f = threadIdx.x;
  int e0 = rowptr[n], e1 = rowptr[n+1];
  float acc = 0.f;
  for (int e=e0;e<e1;e++){
    int s = csr[e];
    acc += dis[s] * ph1[s*128 + f];
  }
  s2[f] = -dis[n]*acc;
  s1[f] = ph1[n*128 + f];
  __syncthreads();
  float a = 0.f;
  for (int k=0;k<128;k++)
    a += s1[k]*W21[k*128+f] + 2.f*s2[k]*W22[k*128+f];
  hcx[n*128 + f] = a;
}

// ---------------- fused GRU step, MFMA (fp16 in, fp32 acc) ----------------
// out^T orientation: C[f][n]; A = Wext rows (global), B = activations (per-wave LDS).
// Wave = 16 nodes x all 128 features. No __syncthreads anywhere.

template<int S>
__device__ __forceinline__ void mm_stage(
  const _Float16* __restrict__ Wst, const _Float16* __restrict__ Bbuf,
  _Float16* __restrict__ hcL, _Float16* __restrict__ zL,
  float* __restrict__ h, const float* __restrict__ hcx,
  int gbase, int lane)
{
  int n16 = lane & 15, g = lane >> 4;
  int q8 = g*8;
  h8 bf[5];
  #pragma unroll
  for (int ks=0;ks<5;ks++)
    bf[ks] = *(const h8*)&Bbuf[n16*HSTRIDE + ks*32 + q8];

  #pragma unroll
  for (int fp=0; fp<4; fp++){
    f4 acc0 = {0.f,0.f,0.f,0.f}, acc1 = {0.f,0.f,0.f,0.f};
    const _Float16* Wa = Wst + (size_t)(fp*32 + n16)*160 + q8;
    #pragma unroll
    for (int ks=0; ks<5; ks++){
      h8 a0 = *(const h8*)(Wa + ks*32);
      h8 a1 = *(const h8*)(Wa + 16*160 + ks*32);
      acc0 = __builtin_amdgcn_mfma_f32_16x16x32_f16(a0, bf[ks], acc0, 0,0,0);
      acc1 = __builtin_amdgcn_mfma_f32_16x16x32_f16(a1, bf[ks], acc1, 0,0,0);
    }
    #pragma unroll
    for (int hh=0; hh<2; hh++){
      f4 acc = hh ? acc1 : acc0;
      int fb = fp*32 + hh*16 + g*4;         // 4 consecutive features fb..fb+3
      if (S == 0){
        int gi = gbase + n16;
        if (gi < Nn){
          f4 hx = *(const f4*)&hcx[(size_t)gi*128 + fb];
          acc += hx;
        }
        h4 o;
        #pragma unroll
        for (int r=0;r<4;r++) o[r] = (_Float16)acc[r];
        *(h4*)&hcL[n16*HSTRIDE + fb] = o;
      } else if (S == 1){
        h4 o;
        #pragma unroll
        for (int r=0;r<4;r++) o[r] = (_Float16)sigm1(acc[r]);
        *(h4*)&zL[n16*ZSTRIDE + fb] = o;
      } else if (S == 2){
        h4 hcv = *(const h4*)&hcL[n16*HSTRIDE + fb];
        h4 o;
        #pragma unroll
        for (int r=0;r<4;r++) o[r] = (_Float16)(sigm1(acc[r]) * (float)hcv[r]);
        *(h4*)&hcL[n16*HSTRIDE + fb] = o;
      } else {
        int gi = gbase + n16;
        f4 hold = *(const f4*)&h[(size_t)gi*128 + fb];
        h4 zv = *(const h4*)&zL[n16*ZSTRIDE + fb];
        f4 out;
        #pragma unroll
        for (int r=0;r<4;r++){
          float z = (float)zv[r];
          out[r] = z*hold[r] + (1.f - z)*tanh1(acc[r]);
        }
        *(f4*)&h[(size_t)gi*128 + fb] = out;
      }
    }
  }
}

__global__ __launch_bounds__(256, 2) void k_mainm(
    float* __restrict__ h, const void* __restrict__ x,
    const float* __restrict__ px1, const float* __restrict__ px2,
    const float* __restrict__ hcx, const _Float16* __restrict__ Wext,
    const int* __restrict__ flags, int t)
{
  __shared__ _Float16 smem[4*WAVE_LDS];
  int tid = threadIdx.x;
  int w = tid >> 6, lane = tid & 63;
  int gbase = blockIdx.x*64 + w*16;
  _Float16* hL  = smem + w*WAVE_LDS;
  _Float16* hcL = hL + 16*HSTRIDE;
  _Float16* zL  = hL + 32*HSTRIDE;

  // ---- stage h tile (fp32 global -> fp16 LDS [n][k])
  {
    const float4* hg = (const float4*)(h + (size_t)gbase*128);
    #pragma unroll
    for (int it=0; it<8; ++it){
      int idx = it*64 + lane;
      float4 v = hg[idx];
      int n = idx >> 5, c = (idx & 31)*4;
      h4 hv; hv[0]=(_Float16)v.x; hv[1]=(_Float16)v.y; hv[2]=(_Float16)v.z; hv[3]=(_Float16)v.w;
      *(h4*)&hL[n*HSTRIDE + c] = hv;
    }
  }
  // ---- K-extension slots: hL gets [1,0...]; hcL gets [u0..u5, 1, 0...]
  if (lane < 16){
    int n = lane;
    for (int k=128;k<160;k++){ hL[n*HSTRIDE+k]=(_Float16)0.f; hcL[n*HSTRIDE+k]=(_Float16)0.f; }
    hL[n*HSTRIDE+128] = (_Float16)1.f;
    int isbf = flags[0];
    int i = gbase + n;
    int b = i / Nn, nn = i - b*Nn;
    size_t xb = ((size_t)(b*Tt + t)*Nn + nn)*2;
    float x0 = ldf(x,xb+0,isbf), x1 = ldf(x,xb+1,isbf);
    float u1a=0.f,u1b=0.f,u2a=-x0,u2b=-x1;     // nodes >= Nn: Tx1=0, Tx2=-x
    if (i < Nn){
      u1a = px1[(t*Nn+i)*2+0]; u1b = px1[(t*Nn+i)*2+1];
      u2a = 2.f*px2[(t*Nn+i)*2+0] - x0; u2b = 2.f*px2[(t*Nn+i)*2+1] - x1;
    }
    hcL[n*HSTRIDE+128]=(_Float16)x0;  hcL[n*HSTRIDE+129]=(_Float16)x1;
    hcL[n*HSTRIDE+130]=(_Float16)u1a; hcL[n*HSTRIDE+131]=(_Float16)u1b;
    hcL[n*HSTRIDE+132]=(_Float16)u2a; hcL[n*HSTRIDE+133]=(_Float16)u2b;
    hcL[n*HSTRIDE+134]=(_Float16)1.f;
  }
  // waves are fully independent: no barrier needed (same-wave LDS ordering via waitcnt)

  mm_stage<0>(Wext + 0*20480, hL,  hcL, zL, h, hcx, gbase, lane);
  mm_stage<1>(Wext + 1*20480, hcL, hcL, zL, h, hcx, gbase, lane);
  mm_stage<2>(Wext + 2*20480, hcL, hcL, zL, h, hcx, gbase, lane);
  mm_stage<3>(Wext + 3*20480, hcL, hcL, zL, h, hcx, gbase, lane);
}

// ---------------- output projection ----------------

__global__ __launch_bounds__(256) void k_out(
  const float* __restrict__ h, const void* __restrict__ Wo,
  const void* __restrict__ bo, void* __restrict__ out,
  const int* __restrict__ flags)
{
  int i = blockIdx.x*256 + threadIdx.x;
  int isbf = flags[0];
  if (i < NTt){
    float acc[HORc];
    #pragma unroll
    for (int j=0;j<HORc;j++) acc[j] = ldf(bo,j,isbf);
    const float* hp = h + (size_t)i*128;
    for (int k=0;k<128;k++){
      float hv = hp[k];
      #pragma unroll
      for (int j=0;j<HORc;j++) acc[j] += hv * ldf(Wo,(size_t)k*HORc+j,isbf);
    }
    int b = i / Nn, n = i - b*Nn;
    #pragma unroll
    for (int j=0;j<HORc;j++){
      size_t oi = (size_t)(b*HORc+j)*Nn + n;
      if (isbf) ((__hip_bfloat16*)out)[oi] = __float2bfloat16(acc[j]);
      else      ((float*)out)[oi] = acc[j];
    }
  }
}

// ---------------- host ----------------

extern "C" void kernel_launch(void* const* d_in, const int* in_sizes, int n_in,
                              void* d_out, int out_size, void* d_ws, size_t ws_size,
                              hipStream_t stream) {
  (void)in_sizes; (void)n_in; (void)out_size; (void)ws_size;
  const void* x   = d_in[0];
  const int*  edge= (const int*)d_in[1];
  const void* W1  = d_in[2];
  const void* b1  = d_in[3];
  const void* W2  = d_in[4];
  const void* b2  = d_in[5];
  const void* Wz  = d_in[6];
  const void* bz  = d_in[7];
  const void* Wr  = d_in[8];
  const void* br  = d_in[9];
  const void* Wc  = d_in[10];
  const void* bc  = d_in[11];
  const void* Wo  = d_in[12];
  const void* bo  = d_in[13];

  char* ws = (char*)d_ws;
  size_t off = 0;
  auto alloc = [&](size_t bytes)->char*{
    char* p = ws + off;
    off += (bytes + 255) & ~(size_t)255;
    return p;
  };
  float* h     = (float*)alloc((size_t)NTt*128*4);   // 81.92 MB, zeroed
  int*   deg   = (int*)  alloc(Nn*4);                // zeroed
  int*   cnt   = (int*)  alloc(Nn*4);                // zeroed
  int*   fillc = (int*)  alloc(Nn*4);                // zeroed
  size_t zlen = off;
  int*   flags = (int*)  alloc(16*4);
  float* dis   = (float*)alloc(Nn*4);
  int*   rowptr= (int*)  alloc((Nn+1)*4);
  int*   csr   = (int*)  alloc(Ee*4);
  float* px1   = (float*)alloc((size_t)Tt*Nn*2*4);
  float* px2   = (float*)alloc((size_t)Tt*Nn*2*4);
  float* ph1   = (float*)alloc((size_t)Nn*128*4);
  float* hcx   = (float*)alloc((size_t)Nn*128*4);
  float* W21   = (float*)alloc(128*128*4);
  float* W22   = (float*)alloc(128*128*4);
  _Float16* Wext = (_Float16*)alloc((size_t)4*128*160*2);  // 160 KB

  hipMemsetAsync(d_ws, 0, zlen, stream);

  k_detect <<<1,256,0,stream>>>(W2, edge, flags);
  k_deg_cnt<<<(Ee+255)/256,256,0,stream>>>(edge, deg, cnt, flags);
  k_dis    <<<(Nn+255)/256,256,0,stream>>>(deg, dis);
  k_scan   <<<1,1024,0,stream>>>(cnt, rowptr);
  k_fill   <<<(Ee+255)/256,256,0,stream>>>(edge, rowptr, fillc, csr, flags);
  k_wext   <<<2,256,0,stream>>>(W1,b1,W2,b2,Wz,bz,Wr,br,Wc,bc, Wext, flags);
  k_w2     <<<64,256,0,stream>>>(W2, W21, W22, flags);
  k_px1    <<<(Tt*Nn+255)/256,256,0,stream>>>(x, dis, rowptr, csr, px1, flags);
  k_px2    <<<(Tt*Nn+255)/256,256,0,stream>>>(px1, dis, rowptr, csr, px2);

  for (int t=0; t<Tt; ++t){
    k_ph1   <<<Nn,128,0,stream>>>(h, dis, rowptr, csr, ph1);
    k_ph2hcx<<<Nn,128,0,stream>>>(ph1, dis, rowptr, csr, W21, W22, hcx);
    k_mainm <<<NTt/64,256,0,stream>>>(h, x, px1, px2, hcx, Wext, flags, t);
  }

  k_out<<<(NTt+255)/256,256,0,stream>>>(h, Wo, bo, d_out, flags);
}

// Round 4
// 1497.549 us; speedup vs baseline: 3.5676x; 1.5413x over previous
//
#include <hip/hip_runtime.h>
#include <hip/hip_bf16.h>

// Problem constants (from reference)
#define Bb  32
#define Tt  12
#define Nn  5000
#define INc 2
#define Hh  128
#define HORc 12
#define Ee  80000
#define NTt (Bb*Nn)   // 160000

typedef float f4  __attribute__((ext_vector_type(4)));
typedef _Float16 h8 __attribute__((ext_vector_type(8)));
typedef _Float16 h4 __attribute__((ext_vector_type(4)));
typedef _Float16 h2 __attribute__((ext_vector_type(2)));

// per-wave LDS (halfs): hcL[32][172] | zL[32][136]
#define HSTRIDE 172
#define ZSTRIDE 136
#define WAVE_LDS (32*HSTRIDE + 32*ZSTRIDE)   // 9856 halfs = 19712 B

__device__ __forceinline__ float ldf(const void* p, size_t i, int isbf){
  return isbf ? __bfloat162float(((const __hip_bfloat16*)p)[i]) : ((const float*)p)[i];
}
__device__ __forceinline__ int eidx(const int* e, int i, int is64){
  return is64 ? e[2*i] : e[i];
}
__device__ __forceinline__ float sigm1(float x){
  x = fmaxf(-30.f, fminf(30.f, x));
  return 1.f/(1.f+__expf(-x));
}
__device__ __forceinline__ float tanh1(float x){
  x = fmaxf(-15.f, fminf(15.f, x));
  float e = __expf(-2.f*x);
  return (1.f-e)/(1.f+e);
}

// ---------------- dtype detection ----------------
__global__ __launch_bounds__(256) void k_detect(const void* W2raw, const int* edge32, int* flags){
  __shared__ int cnt_bf, cnt_odd;
  if (threadIdx.x==0){ cnt_bf=0; cnt_odd=0; }
  __syncthreads();
  {
    unsigned w = ((const unsigned*)W2raw)[threadIdx.x];
    unsigned hb = (w>>8)&0x7Fu;
    if (hb>=0x34u && hb<=0x3Fu) atomicAdd(&cnt_bf,1);
  }
  if (threadIdx.x < 128){
    if (edge32[2*threadIdx.x+1] != 0) atomicAdd(&cnt_odd,1);
  }
  __syncthreads();
  if (threadIdx.x==0){
    flags[0] = (cnt_bf >= 128) ? 1 : 0;
    flags[1] = (cnt_odd == 0) ? 1 : 0;
  }
}

// ---------------- graph precompute ----------------
__global__ __launch_bounds__(256) void k_deg_cnt(const int* __restrict__ edge, int* deg, int* cnt,
                                                 const int* __restrict__ flags){
  int id = blockIdx.x*256 + threadIdx.x;
  int is64 = flags[1];
  if (id < Ee){
    atomicAdd(&deg[eidx(edge, id, is64)], 1);
    atomicAdd(&cnt[eidx(edge, Ee+id, is64)], 1);
  }
}

__global__ __launch_bounds__(256) void k_dis(const int* __restrict__ deg, float* dis){
  int id = blockIdx.x*256 + threadIdx.x;
  if (id < Nn){
    int d = deg[id];
    dis[id] = d > 0 ? rsqrtf((float)d) : 0.f;
  }
}

__global__ __launch_bounds__(1024) void k_scan(const int* __restrict__ cnt, int* rowptr){
  __shared__ int part[1024];
  int t = threadIdx.x;
  int base = t*5;
  int s = 0;
  #pragma unroll
  for (int j=0;j<5;j++){ int idx=base+j; if (idx<Nn) s += cnt[idx]; }
  part[t] = s; __syncthreads();
  for (int off=1; off<1024; off<<=1){
    int add = (t>=off) ? part[t-off] : 0;
    __syncthreads();
    part[t] += add;
    __syncthreads();
  }
  int run = (t>0) ? part[t-1] : 0;
  #pragma unroll
  for (int j=0;j<5;j++){
    int idx = base+j;
    if (idx < Nn){ rowptr[idx] = run; run += cnt[idx]; }
  }
  if (t == 1023) rowptr[Nn] = part[1023];
}

__global__ __launch_bounds__(256) void k_fill(const int* __restrict__ edge,
                                              const int* __restrict__ rowptr,
                                              int* fillc, int* csr,
                                              const int* __restrict__ flags){
  int id = blockIdx.x*256 + threadIdx.x;
  int is64 = flags[1];
  if (id < Ee){
    int d = eidx(edge, Ee+id, is64);
    int pos = atomicAdd(&fillc[d], 1);
    csr[rowptr[d] + pos] = eidx(edge, id, is64);
  }
}

// ---------------- weight precompute (element-parallel) ----------------
// Wext: 4 stage matrices [128 f][160 k] fp16 (A-operand, transposed weights).
// Whc:  [128 f][256 k] fp16 = [W2[1]^T | 2*W2[2]^T]  (graph hc correction, K-folded).
__global__ __launch_bounds__(128) void k_wx(
  const void* __restrict__ W1, const void* __restrict__ b1,
  const void* __restrict__ W2, const void* __restrict__ b2,
  const void* __restrict__ Wz, const void* __restrict__ bz,
  const void* __restrict__ Wr, const void* __restrict__ br,
  const void* __restrict__ Wc, const void* __restrict__ bc,
  _Float16* __restrict__ Wext, _Float16* __restrict__ Whc,
  const int* __restrict__ flags)
{
  int bid = blockIdx.x, f = threadIdx.x;
  int isbf = flags[0];
  if (bid < 640){
    int s = bid/160, k = bid - s*160;
    float v = 0.f;
    if (k < 128){
      if (s == 0)
        v = ldf(W2,(size_t)k*128+f,isbf) - ldf(W2,(size_t)(2*128+k)*128+f,isbf);
      else {
        const void* Wg = (s==1)?Wz:((s==2)?Wr:Wc);
        v = ldf(Wg,(size_t)(128+k)*128+f,isbf);
      }
    } else if (s == 0){
      v = (k==128) ? ldf(b2,f,isbf) : 0.f;
    } else if (k < 134){
      const void* Wg = (s==1)?Wz:((s==2)?Wr:Wc);
      int q = k - 128;
      float acc = 0.f;
      for (int j=0;j<128;j++) acc += ldf(W1,(size_t)q*128+j,isbf)*ldf(Wg,(size_t)j*128+f,isbf);
      v = acc;
    } else if (k == 134){
      const void* Wg = (s==1)?Wz:((s==2)?Wr:Wc);
      const void* bg = (s==1)?bz:((s==2)?br:bc);
      float acc = ldf(bg,f,isbf);
      for (int j=0;j<128;j++) acc += ldf(b1,j,isbf)*ldf(Wg,(size_t)j*128+f,isbf);
      v = acc;
    }
    Wext[(size_t)(s*128+f)*160 + k] = (_Float16)v;
  } else {
    int k = bid - 640;  // 0..255
    float v = (k < 128) ? ldf(W2,(size_t)(128+k)*128+f,isbf)
                        : 2.f*ldf(W2,(size_t)(2*128+(k-128))*128+f,isbf);
    Whc[(size_t)f*256 + k] = (_Float16)v;
  }
}

// ---------------- x propagation (all timesteps at once) ----------------
__global__ __launch_bounds__(256) void k_px1(
  const void* __restrict__ x, const float* __restrict__ dis,
  const int* __restrict__ rowptr, const int* __restrict__ csr, float* __restrict__ px1,
  const int* __restrict__ flags)
{
  int id = blockIdx.x*256 + threadIdx.x;
  int isbf = flags[0];
  if (id < Tt*Nn){
    int t = id / Nn, n = id - t*Nn;
    int e0 = rowptr[n], e1 = rowptr[n+1];
    float a0=0.f, a1=0.f;
    for (int e=e0;e<e1;e++){
      int s = csr[e]; float ds = dis[s];
      size_t xb = (size_t)(t*Nn+s)*2;
      a0 += ds*ldf(x,xb+0,isbf); a1 += ds*ldf(x,xb+1,isbf);
    }
    float dn = -dis[n];
    px1[id*2+0] = dn*a0; px1[id*2+1] = dn*a1;
  }
}

__global__ __launch_bounds__(256) void k_px2(
  const float* __restrict__ px1, const float* __restrict__ dis,
  const int* __restrict__ rowptr, const int* __restrict__ csr, float* __restrict__ px2)
{
  int id = blockIdx.x*256 + threadIdx.x;
  if (id < Tt*Nn){
    int t = id / Nn, n = id - t*Nn;
    int e0 = rowptr[n], e1 = rowptr[n+1];
    float a0=0.f, a1=0.f;
    for (int e=e0;e<e1;e++){
      int s = csr[e]; float ds = dis[s];
      const float* pp = px1 + (size_t)(t*Nn+s)*2;
      a0 += ds*pp[0]; a1 += ds*pp[1];
    }
    float dn = -dis[n];
    px2[id*2+0] = dn*a0; px2[id*2+1] = dn*a1;
  }
}

// ---------------- per-step h propagation (fp16, 2 nodes/block) ----------------
// phh[n][0..127] = ph1, phh[n][128..255] = ph2 (fp16 rows of 256)
__global__ __launch_bounds__(128) void k_ph1(
  const _Float16* __restrict__ h16, const float* __restrict__ dis,
  const int* __restrict__ rowptr, const int* __restrict__ csr,
  _Float16* __restrict__ phh)
{
  int n = blockIdx.x*2 + (threadIdx.x>>6);
  int f2 = threadIdx.x & 63;
  int e0 = rowptr[n], e1 = rowptr[n+1];
  float a0=0.f, a1=0.f;
  for (int e=e0;e<e1;e++){
    int s = csr[e]; float ds = dis[s];
    h2 v = *(const h2*)(h16 + (size_t)s*128 + 2*f2);
    a0 += ds*(float)v[0]; a1 += ds*(float)v[1];
  }
  float dn = -dis[n];
  h2 o; o[0]=(_Float16)(dn*a0); o[1]=(_Float16)(dn*a1);
  *(h2*)(phh + (size_t)n*256 + 2*f2) = o;
}

__global__ __launch_bounds__(128) void k_ph2(
  const float* __restrict__ dis,
  const int* __restrict__ rowptr, const int* __restrict__ csr,
  _Float16* __restrict__ phh)
{
  int n = blockIdx.x*2 + (threadIdx.x>>6);
  int f2 = threadIdx.x & 63;
  int e0 = rowptr[n], e1 = rowptr[n+1];
  float a0=0.f, a1=0.f;
  for (int e=e0;e<e1;e++){
    int s = csr[e]; float ds = dis[s];
    h2 v = *(const h2*)(phh + (size_t)s*256 + 2*f2);
    a0 += ds*(float)v[0]; a1 += ds*(float)v[1];
  }
  float dn = -dis[n];
  h2 o; o[0]=(_Float16)(dn*a0); o[1]=(_Float16)(dn*a1);
  *(h2*)(phh + (size_t)n*256 + 128 + 2*f2) = o;
}

// ---------------- fused GRU step, MFMA ----------------
// Wave = 32 nodes (2 tiles of 16) x all 128 features. out^T: C[f][n].
// A = Wext/Whc rows from global (L1/L2-hot); B = activations (global h16 / per-wave LDS).
// No __syncthreads anywhere.

__device__ __forceinline__ void load_b(const _Float16* hcL, h8 (&bf)[2][5], int lane){
  int n16 = lane & 15, q8 = (lane>>4)*8;
  #pragma unroll
  for (int tl=0;tl<2;tl++)
    #pragma unroll
    for (int ks=0;ks<5;ks++)
      bf[tl][ks] = *(const h8*)&hcL[(tl*16+n16)*HSTRIDE + ks*32 + q8];
}

// stage 0: hc = h@(W2[0]-W2[2]) + b2 (+ graph K-ext for nodes < Nn)
__device__ __forceinline__ void st0(
  const _Float16* __restrict__ Wst, const _Float16* __restrict__ Whc,
  const _Float16* __restrict__ h16, const _Float16* __restrict__ phh,
  _Float16* __restrict__ hcL, int gbase, int lane)
{
  int n16 = lane & 15, g = lane >> 4, q8 = g*8;
  h8 zz = {0,0,0,0,0,0,0,0};
  h8 bf[2][5];
  #pragma unroll
  for (int tl=0;tl<2;tl++){
    const _Float16* hp = h16 + (size_t)(gbase + tl*16 + n16)*128 + q8;
    #pragma unroll
    for (int ks=0;ks<4;ks++) bf[tl][ks] = *(const h8*)(hp + ks*32);
    h8 e = zz;
    if (g==0) e[0] = (_Float16)1.f;   // bias slot k=128
    bf[tl][4] = e;
  }
  bool graph = (gbase < Nn);          // wave-uniform
  h8 bg[2][8];
  if (graph){
    #pragma unroll
    for (int tl=0;tl<2;tl++){
      int node = gbase + tl*16 + n16;
      int row = node < Nn ? node : 0;
      bool ok = node < Nn;
      const _Float16* pp = phh + (size_t)row*256 + q8;
      #pragma unroll
      for (int ks=0;ks<8;ks++){
        h8 v = *(const h8*)(pp + ks*32);
        bg[tl][ks] = ok ? v : zz;
      }
    }
  }
  f4 z4 = {0.f,0.f,0.f,0.f};
  #pragma unroll
  for (int fp=0; fp<4; fp++){
    f4 acc[2][2];
    #pragma unroll
    for (int tl=0;tl<2;tl++){ acc[tl][0]=z4; acc[tl][1]=z4; }
    const _Float16* Wa = Wst + (size_t)(fp*32 + n16)*160 + q8;
    #pragma unroll
    for (int ks=0; ks<5; ks++){
      h8 a0 = *(const h8*)(Wa + ks*32);
      h8 a1 = *(const h8*)(Wa + 16*160 + ks*32);
      #pragma unroll
      for (int tl=0;tl<2;tl++){
        acc[tl][0] = __builtin_amdgcn_mfma_f32_16x16x32_f16(a0, bf[tl][ks], acc[tl][0], 0,0,0);
        acc[tl][1] = __builtin_amdgcn_mfma_f32_16x16x32_f16(a1, bf[tl][ks], acc[tl][1], 0,0,0);
      }
    }
    if (graph){
      const _Float16* Wb = Whc + (size_t)(fp*32 + n16)*256 + q8;
      #pragma unroll
      for (int ks=0; ks<8; ks++){
        h8 a0 = *(const h8*)(Wb + ks*32);
        h8 a1 = *(const h8*)(Wb + 16*256 + ks*32);
        #pragma unroll
        for (int tl=0;tl<2;tl++){
          acc[tl][0] = __builtin_amdgcn_mfma_f32_16x16x32_f16(a0, bg[tl][ks], acc[tl][0], 0,0,0);
          acc[tl][1] = __builtin_amdgcn_mfma_f32_16x16x32_f16(a1, bg[tl][ks], acc[tl][1], 0,0,0);
        }
      }
    }
    #pragma unroll
    for (int tl=0;tl<2;tl++)
      #pragma unroll
      for (int hh=0;hh<2;hh++){
        int fb = fp*32 + hh*16 + g*4;
        f4 a = acc[tl][hh];
        h4 o;
        #pragma unroll
        for (int r=0;r<4;r++) o[r] = (_Float16)a[r];
        *(h4*)&hcL[(tl*16+n16)*HSTRIDE + fb] = o;
      }
  }
}

// stages 1(z) / 2(r, overwrite hcL with r*hc) / 3(c + blend, write h16)
template<int S>
__device__ __forceinline__ void mm_stage(
  const _Float16* __restrict__ Wst, const h8 (&bf)[2][5],
  _Float16* __restrict__ hcL, _Float16* __restrict__ zL,
  _Float16* __restrict__ h16, int gbase, int lane)
{
  int n16 = lane & 15, g = lane >> 4, q8 = g*8;
  f4 z4 = {0.f,0.f,0.f,0.f};
  #pragma unroll
  for (int fp=0; fp<4; fp++){
    f4 acc[2][2];
    #pragma unroll
    for (int tl=0;tl<2;tl++){ acc[tl][0]=z4; acc[tl][1]=z4; }
    const _Float16* Wa = Wst + (size_t)(fp*32 + n16)*160 + q8;
    #pragma unroll
    for (int ks=0; ks<5; ks++){
      h8 a0 = *(const h8*)(Wa + ks*32);
      h8 a1 = *(const h8*)(Wa + 16*160 + ks*32);
      #pragma unroll
      for (int tl=0;tl<2;tl++){
        acc[tl][0] = __builtin_amdgcn_mfma_f32_16x16x32_f16(a0, bf[tl][ks], acc[tl][0], 0,0,0);
        acc[tl][1] = __builtin_amdgcn_mfma_f32_16x16x32_f16(a1, bf[tl][ks], acc[tl][1], 0,0,0);
      }
    }
    #pragma unroll
    for (int tl=0;tl<2;tl++)
      #pragma unroll
      for (int hh=0;hh<2;hh++){
        int fb = fp*32 + hh*16 + g*4;
        int nn = tl*16 + n16;
        f4 a = acc[tl][hh];
        if (S == 1){
          h4 o;
          #pragma unroll
          for (int r=0;r<4;r++) o[r] = (_Float16)sigm1(a[r]);
          *(h4*)&zL[nn*ZSTRIDE + fb] = o;
        } else if (S == 2){
          h4 hcv = *(const h4*)&hcL[nn*HSTRIDE + fb];
          h4 o;
          #pragma unroll
          for (int r=0;r<4;r++) o[r] = (_Float16)(sigm1(a[r]) * (float)hcv[r]);
          *(h4*)&hcL[nn*HSTRIDE + fb] = o;
        } else {
          int gi = gbase + nn;
          h4 ho = *(const h4*)(h16 + (size_t)gi*128 + fb);
          h4 zv = *(const h4*)&zL[nn*ZSTRIDE + fb];
          h4 o;
          #pragma unroll
          for (int r=0;r<4;r++){
            float z = (float)zv[r];
            o[r] = (_Float16)(z*(float)ho[r] + (1.f - z)*tanh1(a[r]));
          }
          *(h4*)(h16 + (size_t)gi*128 + fb) = o;
        }
      }
  }
}

__global__ __launch_bounds__(256, 2) void k_mainm(
    _Float16* __restrict__ h16, const void* __restrict__ x,
    const float* __restrict__ px1, const float* __restrict__ px2,
    const _Float16* __restrict__ phh,
    const _Float16* __restrict__ Wext, const _Float16* __restrict__ Whc,
    const int* __restrict__ flags, int t)
{
  __shared__ _Float16 smem[4*WAVE_LDS];   // 78848 B -> 2 blocks/CU
  int tid = threadIdx.x;
  int w = tid >> 6, lane = tid & 63;
  int gbase = blockIdx.x*128 + w*32;
  _Float16* hcL = smem + w*WAVE_LDS;
  _Float16* zL  = hcL + 32*HSTRIDE;

  // K-extension slots for gate stages: hcL[n][128..134] = {x0,x1,u1a,u1b,u2a,u2b,1}, 135..159 = 0
  if (lane < 32){
    int n = lane;
    _Float16* row = hcL + n*HSTRIDE;
    for (int k=135;k<160;k++) row[k] = (_Float16)0.f;
    int isbf = flags[0];
    int i = gbase + n;
    int b = i / Nn, nn2 = i - b*Nn;
    size_t xb = ((size_t)(b*Tt + t)*Nn + nn2)*2;
    float x0 = ldf(x,xb+0,isbf), x1 = ldf(x,xb+1,isbf);
    float u1a=0.f,u1b=0.f,u2a=-x0,u2b=-x1;   // nodes >= Nn: Tx1=0, Tx2=-x
    if (i < Nn){
      u1a = px1[(t*Nn+i)*2+0]; u1b = px1[(t*Nn+i)*2+1];
      u2a = 2.f*px2[(t*Nn+i)*2+0] - x0; u2b = 2.f*px2[(t*Nn+i)*2+1] - x1;
    }
    row[128]=(_Float16)x0;  row[129]=(_Float16)x1;
    row[130]=(_Float16)u1a; row[131]=(_Float16)u1b;
    row[132]=(_Float16)u2a; row[133]=(_Float16)u2b;
    row[134]=(_Float16)1.f;
  }
  // waves fully independent; same-wave LDS ordering handled by waitcnt

  st0(Wext, Whc, h16, phh, hcL, gbase, lane);

  h8 ba[2][5];
  load_b(hcL, ba, lane);
  mm_stage<1>(Wext + 1*20480, ba, hcL, zL, h16, gbase, lane);
  mm_stage<2>(Wext + 2*20480, ba, hcL, zL, h16, gbase, lane);

  h8 bc[2][5];
  load_b(hcL, bc, lane);
  mm_stage<3>(Wext + 3*20480, bc, hcL, zL, h16, gbase, lane);
}

// ---------------- output projection ----------------
__global__ __launch_bounds__(256) void k_out(
  const _Float16* __restrict__ h16, const void* __restrict__ Wo,
  const void* __restrict__ bo, void* __restrict__ out,
  const int* __restrict__ flags)
{
  __shared__ float wol[128*HORc];
  __shared__ float wob[HORc];
  int isbf = flags[0];
  for (int idx=threadIdx.x; idx<128*HORc; idx+=256) wol[idx] = ldf(Wo, idx, isbf);
  if (threadIdx.x < HORc) wob[threadIdx.x] = ldf(bo, threadIdx.x, isbf);
  __syncthreads();

  int i = blockIdx.x*256 + threadIdx.x;
  if (i < NTt){
    float acc[HORc];
    #pragma unroll
    for (int j=0;j<HORc;j++) acc[j] = wob[j];
    const _Float16* hp = h16 + (size_t)i*128;
    for (int kb=0;kb<16;kb++){
      h8 hv = *(const h8*)(hp + kb*8);
      #pragma unroll
      for (int j=0;j<8;j++){
        float hvf = (float)hv[j];
        #pragma unroll
        for (int jj=0;jj<HORc;jj++) acc[jj] += hvf * wol[(kb*8+j)*HORc + jj];
      }
    }
    int b = i / Nn, n = i - b*Nn;
    #pragma unroll
    for (int j=0;j<HORc;j++){
      size_t oi = (size_t)(b*HORc+j)*Nn + n;
      if (isbf) ((__hip_bfloat16*)out)[oi] = __float2bfloat16(acc[j]);
      else      ((float*)out)[oi] = acc[j];
    }
  }
}

// ---------------- host ----------------
extern "C" void kernel_launch(void* const* d_in, const int* in_sizes, int n_in,
                              void* d_out, int out_size, void* d_ws, size_t ws_size,
                              hipStream_t stream) {
  (void)in_sizes; (void)n_in; (void)out_size; (void)ws_size;
  const void* x   = d_in[0];
  const int*  edge= (const int*)d_in[1];
  const void* W1  = d_in[2];
  const void* b1  = d_in[3];
  const void* W2  = d_in[4];
  const void* b2  = d_in[5];
  const void* Wz  = d_in[6];
  const void* bz  = d_in[7];
  const void* Wr  = d_in[8];
  const void* br  = d_in[9];
  const void* Wc  = d_in[10];
  const void* bc  = d_in[11];
  const void* Wo  = d_in[12];
  const void* bo  = d_in[13];

  char* ws = (char*)d_ws;
  size_t off = 0;
  auto alloc = [&](size_t bytes)->char*{
    char* p = ws + off;
    off += (bytes + 255) & ~(size_t)255;
    return p;
  };
  _Float16* h16  = (_Float16*)alloc((size_t)NTt*128*2);   // 41 MB, zeroed
  int*   deg   = (int*)  alloc(Nn*4);                     // zeroed
  int*   cnt   = (int*)  alloc(Nn*4);                     // zeroed
  int*   fillc = (int*)  alloc(Nn*4);                     // zeroed
  size_t zlen = off;
  int*   flags = (int*)  alloc(16*4);
  float* dis   = (float*)alloc(Nn*4);
  int*   rowptr= (int*)  alloc((Nn+1)*4);
  int*   csr   = (int*)  alloc(Ee*4);
  float* px1   = (float*)alloc((size_t)Tt*Nn*2*4);
  float* px2   = (float*)alloc((size_t)Tt*Nn*2*4);
  _Float16* phh  = (_Float16*)alloc((size_t)5120*256*2);  // ph1|ph2 fp16 rows (padded)
  _Float16* Wext = (_Float16*)alloc((size_t)4*128*160*2);
  _Float16* Whc  = (_Float16*)alloc((size_t)128*256*2);

  hipMemsetAsync(d_ws, 0, zlen, stream);

  k_detect <<<1,256,0,stream>>>(W2, edge, flags);
  k_deg_cnt<<<(Ee+255)/256,256,0,stream>>>(edge, deg, cnt, flags);
  k_dis    <<<(Nn+255)/256,256,0,stream>>>(deg, dis);
  k_scan   <<<1,1024,0,stream>>>(cnt, rowptr);
  k_fill   <<<(Ee+255)/256,256,0,stream>>>(edge, rowptr, fillc, csr, flags);
  k_wx     <<<896,128,0,stream>>>(W1,b1,W2,b2,Wz,bz,Wr,br,Wc,bc, Wext, Whc, flags);
  k_px1    <<<(Tt*Nn+255)/256,256,0,stream>>>(x, dis, rowptr, csr, px1, flags);
  k_px2    <<<(Tt*Nn+255)/256,256,0,stream>>>(px1, dis, rowptr, csr, px2);

  for (int t=0; t<Tt; ++t){
    k_ph1  <<<Nn/2,128,0,stream>>>(h16, dis, rowptr, csr, phh);
    k_ph2  <<<Nn/2,128,0,stream>>>(dis, rowptr, csr, phh);
    k_mainm<<<NTt/128,256,0,stream>>>(h16, x, px1, px2, phh, Wext, Whc, flags, t);
  }

  k_out<<<(NTt+255)/256,256,0,stream>>>(h16, Wo, bo, d_out, flags);
}